// Round 8
// baseline (76.193 us; speedup 1.0000x reference)
//
#include <hip/hip_runtime.h>

// s[n,k] = x[n]·coords[k] + ||coords[k]||^2 ; out[n,k] = (second_min_j s[n,j]) > s[n,k]
// 512 blocks x 512 threads (2 blocks/CU, 16 waves/CU). Block: 32 rows x 128 cols.
// wave = K-split g (8 splits x 32 dims). Thread: 8x8 tile. 4 chunks x 8 dims/split.
// xs[32][64] slot-XOR swizzle; cs[64][128] col fold-swizzle; part alias [4][32][132].

__global__ __launch_bounds__(512, 4)
void kmad_main(const float* __restrict__ x, const float* __restrict__ coords,
               int* __restrict__ out) {
    __shared__ float lds[17024];         // 66.5 KB
    float* const cs    = lds;            // [64][128], col f4-slot S stored at S^(S>>3)
    float* const xs    = lds + 8192;     // [32][64], f4-slot sk stored at sk^(row>>3)
    float* const norms = lds + 16896;    // [128]
    float* const part  = lds;            // epilogue alias [4][32][132] = 16896 floats

    const int t  = threadIdx.x;
    const int g  = t >> 6;               // wave = K-split 0..7 (owns dims g*32..+32)
    const int l  = t & 63;
    const int rg = l >> 4;               // 0..3 -> rows rg*8..+8
    const int cg = l & 15;               // 0..15 -> cols cg*8..+8
    const int r0 = rg * 8;
    const int row0 = blockIdx.x * 32;

    const int S0  = cg * 2, S1 = S0 + 1;
    const int pc0 = (S0 ^ (S0 >> 3)) * 4;
    const int pc1 = (S1 ^ (S1 >> 3)) * 4;

    // ---- norms[c] = ||coords[c]||^2 ----
    {
        const int c = t >> 2, h = t & 3;
        const float4* cp = (const float4*)(coords + (size_t)c * 256 + h * 64);
        float na = 0.f;
        #pragma unroll
        for (int k = 0; k < 16; ++k) {
            const float4 v = cp[k];
            na = fmaf(v.x, v.x, na); na = fmaf(v.y, v.y, na);
            na = fmaf(v.z, v.z, na); na = fmaf(v.w, v.w, na);
        }
        na += __shfl_xor(na, 1); na += __shfl_xor(na, 2);
        if (h == 0) norms[c] = na;
    }

    // ---- staging roles ----
    // xs: thread stages 1 f4: row srow, dim-slot sk; slot sk holds dim (sk>>1)*32 + ch*8 + (sk&1)*4
    const int srow = t >> 4, sk = t & 15;
    const int xso  = srow * 64 + ((sk ^ (srow >> 3)) * 4);
    const float* xr = x + (size_t)(row0 + srow) * 256 + ((sk >> 1) * 32 + (sk & 1) * 4);
    // cs: thread stages a 4x4 transpose block: cols cq*4..+4, local dim rows dsel*4..+4
    const int cq = t & 31, dsel = t >> 5;     // dsel 0..15
    const int Pq = (cq ^ (cq >> 3)) * 4;
    const float* crd = coords + (size_t)(cq * 4) * 256
                     + ((dsel >> 1) * 32 + (dsel & 1) * 4);    // + ch*8 at use
    float* const csw = cs + (size_t)(dsel * 4) * 128 + Pq;

#define STAGE(CH) { \
        *(float4*)(xs + xso) = *(const float4*)(xr + (CH) * 8); \
        const float4 u0 = *(const float4*)(crd + (CH) * 8); \
        const float4 u1 = *(const float4*)(crd + (CH) * 8 + 256); \
        const float4 u2 = *(const float4*)(crd + (CH) * 8 + 512); \
        const float4 u3 = *(const float4*)(crd + (CH) * 8 + 768); \
        *(float4*)(csw)       = make_float4(u0.x, u1.x, u2.x, u3.x); \
        *(float4*)(csw + 128) = make_float4(u0.y, u1.y, u2.y, u3.y); \
        *(float4*)(csw + 256) = make_float4(u0.z, u1.z, u2.z, u3.z); \
        *(float4*)(csw + 384) = make_float4(u0.w, u1.w, u2.w, u3.w); \
    }

    STAGE(0)
    __syncthreads();

    float acc[8][8] = {};

    #pragma unroll
    for (int ch = 0; ch < 4; ++ch) {
        #pragma unroll
        for (int dd = 0; dd < 2; ++dd) {
            const int sl = g * 2 + dd;
            const float* br = cs + (size_t)(g * 8 + dd * 4) * 128;
            float4 b0[4], b1[4];
            #pragma unroll
            for (int j = 0; j < 4; ++j) {
                b0[j] = *(const float4*)(br + j * 128 + pc0);
                b1[j] = *(const float4*)(br + j * 128 + pc1);
            }
            #pragma unroll
            for (int i = 0; i < 8; ++i) {
                const float4 a = *(const float4*)(xs + (r0 + i) * 64 + ((sl ^ rg) * 4));
#define STEP(j, av) \
                acc[i][0] = fmaf(av, b0[j].x, acc[i][0]); \
                acc[i][1] = fmaf(av, b0[j].y, acc[i][1]); \
                acc[i][2] = fmaf(av, b0[j].z, acc[i][2]); \
                acc[i][3] = fmaf(av, b0[j].w, acc[i][3]); \
                acc[i][4] = fmaf(av, b1[j].x, acc[i][4]); \
                acc[i][5] = fmaf(av, b1[j].y, acc[i][5]); \
                acc[i][6] = fmaf(av, b1[j].z, acc[i][6]); \
                acc[i][7] = fmaf(av, b1[j].w, acc[i][7]);
                STEP(0, a.x) STEP(1, a.y) STEP(2, a.z) STEP(3, a.w)
#undef STEP
            }
        }
        __syncthreads();
        if (ch < 3) STAGE(ch + 1)
        __syncthreads();
    }
#undef STAGE

    // ---- reduce 8 split-partials via 4 planes, 2 rounds ----
    if (g < 4) {
        float* pl = part + g * 4224 + (size_t)r0 * 132 + cg * 8;
        #pragma unroll
        for (int i = 0; i < 8; ++i) {
            *(float4*)(pl + i * 132)     = make_float4(acc[i][0], acc[i][1], acc[i][2], acc[i][3]);
            *(float4*)(pl + i * 132 + 4) = make_float4(acc[i][4], acc[i][5], acc[i][6], acc[i][7]);
        }
    }
    __syncthreads();
    if (g >= 4) {
        float* pl = part + (g - 4) * 4224 + (size_t)r0 * 132 + cg * 8;
        #pragma unroll
        for (int i = 0; i < 8; ++i) {
            float4 v0 = *(const float4*)(pl + i * 132);
            float4 v1 = *(const float4*)(pl + i * 132 + 4);
            v0.x += acc[i][0]; v0.y += acc[i][1]; v0.z += acc[i][2]; v0.w += acc[i][3];
            v1.x += acc[i][4]; v1.y += acc[i][5]; v1.z += acc[i][6]; v1.w += acc[i][7];
            *(float4*)(pl + i * 132)     = v0;
            *(float4*)(pl + i * 132 + 4) = v1;
        }
    }
    __syncthreads();

    // ---- final: sum 4 planes, +norms, second-min over 128, compare, store ----
    {
        const int frow = t >> 4, seg = t & 15;       // 32 rows x 16 col-segments of 8
        const float* pr = part + (size_t)frow * 132 + seg * 8;
        float s[8];
        #pragma unroll
        for (int u = 0; u < 2; ++u) {
            const float4 a = *(const float4*)(pr + u * 4);
            const float4 b = *(const float4*)(pr + 4224  + u * 4);
            const float4 c = *(const float4*)(pr + 8448  + u * 4);
            const float4 d = *(const float4*)(pr + 12672 + u * 4);
            const float4 n = *(const float4*)(norms + seg * 8 + u * 4);
            s[u * 4 + 0] = (a.x + b.x) + (c.x + d.x) + n.x;
            s[u * 4 + 1] = (a.y + b.y) + (c.y + d.y) + n.y;
            s[u * 4 + 2] = (a.z + b.z) + (c.z + d.z) + n.z;
            s[u * 4 + 3] = (a.w + b.w) + (c.w + d.w) + n.w;
        }
        float m1 = fminf(s[0], s[1]);
        float m2 = fmaxf(s[0], s[1]);
#define UPD(v) { const float hi = fmaxf(m1, (v)); m1 = fminf(m1, (v)); m2 = fminf(m2, hi); }
        UPD(s[2]) UPD(s[3]) UPD(s[4]) UPD(s[5]) UPD(s[6]) UPD(s[7])
#undef UPD
        #pragma unroll
        for (int m = 1; m <= 8; m <<= 1) {   // merge across the 16 seg lanes
            const float o1 = __shfl_xor(m1, m);
            const float o2 = __shfl_xor(m2, m);
            m2 = fminf(fmaxf(m1, o1), fminf(m2, o2));
            m1 = fminf(m1, o1);
        }
        int* op = out + (size_t)(row0 + frow) * 128 + seg * 8;
        int4 o0, o1v;
        o0.x  = m2 > s[0]; o0.y  = m2 > s[1]; o0.z  = m2 > s[2]; o0.w  = m2 > s[3];
        o1v.x = m2 > s[4]; o1v.y = m2 > s[5]; o1v.z = m2 > s[6]; o1v.w = m2 > s[7];
        *(int4*)op       = o0;
        *(int4*)(op + 4) = o1v;
    }
}

extern "C" void kernel_launch(void* const* d_in, const int* in_sizes, int n_in,
                              void* d_out, int out_size, void* d_ws, size_t ws_size,
                              hipStream_t stream) {
    const float* x      = (const float*)d_in[0];   // (16384, 256) fp32
    const float* coords = (const float*)d_in[1];   // (128, 256)   fp32
    int* out = (int*)d_out;                        // (16384, 128) bool -> int32 0/1
    kmad_main<<<512, 512, 0, stream>>>(x, coords, out);
}

// Round 9
// 49.306 us; speedup vs baseline: 1.5453x; 1.5453x over previous
//
#include <hip/hip_runtime.h>

// s[n,k] = x[n]·coords[k] + ||coords[k]||^2 ; out[n,k] = (second_min_j s[n,j]) > s[n,k]
// 256 blocks x 1024 threads (1 block/CU, 16 waves = 4/SIMD). Block: 64 rows x 128 cols.
// K-split 8 (g = t>>7, wave-pair-uniform). Thread: 8x8 tile, 32 dims.
// cst[256][128] LDS-resident (fold-swizzled cols, staged once), xs reg-prefetch dbuf.
// Epilogue: 2-round plane exchange in part[4][64][132] (aliases cst), then second-min.
// __launch_bounds__(1024, 2): VGPR cap = 128 (w=4 capped at 64 and spilled — R7/R8).

__global__ __launch_bounds__(1024, 2)
void kmad_main(const float* __restrict__ x, const float* __restrict__ coords,
               int* __restrict__ out) {
    __shared__ float lds[36992];         // 144.5 KB
    float* const cst   = lds;            // [256][128] fold-swizzled col blocks
    float* const xs    = lds + 32768;    // [2][64][32]
    float* const norms = lds + 36864;    // [128]
    float* const part  = lds;            // epilogue alias [4][64][132] = 33792 floats

    const int t    = threadIdx.x;
    const int g    = t >> 7;                                // K-split 0..7 (wave-uniform)
    const int rg   = ((t >> 6) & 1) * 4 + ((t >> 4) & 3);   // row-group 0..7
    const int cg   = t & 15;                                // col-group 0..15
    const int r0   = rg * 8;
    const int row0 = blockIdx.x * 64;

    // fold-swizzle S -> S ^ (S>>3) on 32 col f4-blocks (bijective; 8-lane groups spread)
    const int S0  = cg * 2, S1 = cg * 2 + 1;
    const int pc0 = (S0 ^ (S0 >> 3)) * 4;
    const int pc1 = (S1 ^ (S1 >> 3)) * 4;
    const int aoff = ((g ^ rg) & 7) * 4;

    // ---- stage cst[d][foldcol] = coords[c][d] (4x4 in-register transpose) ----
    {
        const int cq = t & 31, dqq = t >> 5;
        const int P4 = (cq ^ (cq >> 3)) * 4;
        #pragma unroll
        for (int un = 0; un < 2; ++un) {
            const int dq = dqq + un * 32;
            const float4 v0 = *(const float4*)&coords[(size_t)(cq * 4 + 0) * 256 + dq * 4];
            const float4 v1 = *(const float4*)&coords[(size_t)(cq * 4 + 1) * 256 + dq * 4];
            const float4 v2 = *(const float4*)&coords[(size_t)(cq * 4 + 2) * 256 + dq * 4];
            const float4 v3 = *(const float4*)&coords[(size_t)(cq * 4 + 3) * 256 + dq * 4];
            float* dst = cst + (size_t)(dq * 4) * 128 + P4;
            *(float4*)(dst)       = make_float4(v0.x, v1.x, v2.x, v3.x);
            *(float4*)(dst + 128) = make_float4(v0.y, v1.y, v2.y, v3.y);
            *(float4*)(dst + 256) = make_float4(v0.z, v1.z, v2.z, v3.z);
            *(float4*)(dst + 384) = make_float4(v0.w, v1.w, v2.w, v3.w);
        }
    }
    // ---- norms[c] = ||coords[c]||^2 ----
    {
        const int c = t >> 3, pp = t & 7;
        const float4* cp = (const float4*)(coords + (size_t)c * 256 + pp * 32);
        float na = 0.f;
        #pragma unroll
        for (int k = 0; k < 8; ++k) {
            const float4 v = cp[k];
            na = fmaf(v.x, v.x, na); na = fmaf(v.y, v.y, na);
            na = fmaf(v.z, v.z, na); na = fmaf(v.w, v.w, na);
        }
        na += __shfl_xor(na, 1); na += __shfl_xor(na, 2); na += __shfl_xor(na, 4);
        if (pp == 0) norms[c] = na;
    }

    // ---- x staging role (first 512 threads) ----
    const bool stager = (t < 512);
    const int srow = t >> 3, sq = t & 7;
    const float* xrow = x + (size_t)(row0 + srow) * 256;
    const int wsl = ((sq ^ (srow >> 3)) & 7) * 4;
    float4 pf;
    if (stager) {   // chunk 0 straight to LDS
        pf = *(const float4*)&xrow[sq * 4];
        *(float4*)&xs[srow * 32 + wsl] = pf;
    }

    float acc[8][8] = {};

    #pragma unroll 1
    for (int ch = 0; ch < 8; ++ch) {
        const int buf = ch & 1;
        __syncthreads();   // xs[buf] ready (and, at ch0, cst+norms staged)

        if (stager && ch < 7)   // issue next chunk's load early; write after compute
            pf = *(const float4*)&xrow[(ch + 1) * 32 + sq * 4];

        // B fragment: 4 dims x 8 cols (wave-uniform d rows; fold-swizzled cols)
        const float* brow = cst + (size_t)(ch * 32 + g * 4) * 128;
        float4 b[4][2];
        #pragma unroll
        for (int j = 0; j < 4; ++j) {
            b[j][0] = *(const float4*)(brow + j * 128 + pc0);
            b[j][1] = *(const float4*)(brow + j * 128 + pc1);
        }

        // A rows + 8x8x4 FMA
        const float* xb = xs + buf * 2048 + r0 * 32 + aoff;
        #pragma unroll
        for (int i = 0; i < 8; ++i) {
            const float4 ar = *(const float4*)(xb + i * 32);
#define STEP(j, a) \
            acc[i][0] = fmaf(a, b[j][0].x, acc[i][0]); \
            acc[i][1] = fmaf(a, b[j][0].y, acc[i][1]); \
            acc[i][2] = fmaf(a, b[j][0].z, acc[i][2]); \
            acc[i][3] = fmaf(a, b[j][0].w, acc[i][3]); \
            acc[i][4] = fmaf(a, b[j][1].x, acc[i][4]); \
            acc[i][5] = fmaf(a, b[j][1].y, acc[i][5]); \
            acc[i][6] = fmaf(a, b[j][1].z, acc[i][6]); \
            acc[i][7] = fmaf(a, b[j][1].w, acc[i][7]);
            STEP(0, ar.x) STEP(1, ar.y) STEP(2, ar.z) STEP(3, ar.w)
#undef STEP
        }

        if (stager && ch < 7)
            *(float4*)&xs[(buf ^ 1) * 2048 + srow * 32 + wsl] = pf;
    }
    __syncthreads();   // cst/xs dead -> part alias safe

    // ---- round A: g<4 write planes ----
    if (g < 4) {
        float* pl = part + g * 8448 + (size_t)r0 * 132;
        #pragma unroll
        for (int i = 0; i < 8; ++i) {
            *(float4*)(pl + i * 132 + pc0) = make_float4(acc[i][0], acc[i][1], acc[i][2], acc[i][3]);
            *(float4*)(pl + i * 132 + pc1) = make_float4(acc[i][4], acc[i][5], acc[i][6], acc[i][7]);
        }
    }
    __syncthreads();
    // ---- round B: g>=4 accumulate into planes ----
    if (g >= 4) {
        float* pl = part + (g - 4) * 8448 + (size_t)r0 * 132;
        #pragma unroll
        for (int i = 0; i < 8; ++i) {
            float4 v0 = *(const float4*)(pl + i * 132 + pc0);
            float4 v1 = *(const float4*)(pl + i * 132 + pc1);
            v0.x += acc[i][0]; v0.y += acc[i][1]; v0.z += acc[i][2]; v0.w += acc[i][3];
            v1.x += acc[i][4]; v1.y += acc[i][5]; v1.z += acc[i][6]; v1.w += acc[i][7];
            *(float4*)(pl + i * 132 + pc0) = v0;
            *(float4*)(pl + i * 132 + pc1) = v1;
        }
    }
    __syncthreads();

    // ---- final: sum 4 planes, +norms, second-min over 128, compare, store ----
    {
        const int frow = t >> 4, csl = t & 15;
        const int T0 = csl * 2, T1 = csl * 2 + 1;
        const int q0 = (T0 ^ (T0 >> 3)) * 4;
        const int q1 = (T1 ^ (T1 >> 3)) * 4;
        const float* pr = part + (size_t)frow * 132;

        float4 u0 = *(const float4*)(pr + q0);
        float4 u1 = *(const float4*)(pr + 8448 + q0);
        float4 u2 = *(const float4*)(pr + 16896 + q0);
        float4 u3 = *(const float4*)(pr + 25344 + q0);
        float4 w0 = *(const float4*)(pr + q1);
        float4 w1 = *(const float4*)(pr + 8448 + q1);
        float4 w2 = *(const float4*)(pr + 16896 + q1);
        float4 w3 = *(const float4*)(pr + 25344 + q1);
        const float4 n0 = *(const float4*)&norms[csl * 8];
        const float4 n1 = *(const float4*)&norms[csl * 8 + 4];

        const float s0 = (u0.x + u1.x) + (u2.x + u3.x) + n0.x;
        const float s1 = (u0.y + u1.y) + (u2.y + u3.y) + n0.y;
        const float s2 = (u0.z + u1.z) + (u2.z + u3.z) + n0.z;
        const float s3 = (u0.w + u1.w) + (u2.w + u3.w) + n0.w;
        const float s4 = (w0.x + w1.x) + (w2.x + w3.x) + n1.x;
        const float s5 = (w0.y + w1.y) + (w2.y + w3.y) + n1.y;
        const float s6 = (w0.z + w1.z) + (w2.z + w3.z) + n1.z;
        const float s7 = (w0.w + w1.w) + (w2.w + w3.w) + n1.w;

        float m1 = fminf(s0, s1);
        float m2 = fmaxf(s0, s1);
#define UPD(v) { const float hi = fmaxf(m1, (v)); m1 = fminf(m1, (v)); m2 = fminf(m2, hi); }
        UPD(s2) UPD(s3) UPD(s4) UPD(s5) UPD(s6) UPD(s7)
#undef UPD
        #pragma unroll
        for (int m = 1; m <= 8; m <<= 1) {   // merge across the 16 csl lanes (bits 0-3)
            const float o1 = __shfl_xor(m1, m);
            const float o2 = __shfl_xor(m2, m);
            m2 = fminf(fmaxf(m1, o1), fminf(m2, o2));
            m1 = fminf(m1, o1);
        }

        int* op = out + (size_t)(row0 + frow) * 128 + csl * 8;
        int4 o0, o1v;
        o0.x  = m2 > s0; o0.y  = m2 > s1; o0.z  = m2 > s2; o0.w  = m2 > s3;
        o1v.x = m2 > s4; o1v.y = m2 > s5; o1v.z = m2 > s6; o1v.w = m2 > s7;
        *(int4*)op       = o0;
        *(int4*)(op + 4) = o1v;
    }
}

extern "C" void kernel_launch(void* const* d_in, const int* in_sizes, int n_in,
                              void* d_out, int out_size, void* d_ws, size_t ws_size,
                              hipStream_t stream) {
    const float* x      = (const float*)d_in[0];   // (16384, 256) fp32
    const float* coords = (const float*)d_in[1];   // (128, 256)   fp32
    int* out = (int*)d_out;                        // (16384, 128) bool -> int32 0/1
    kmad_main<<<256, 1024, 0, stream>>>(x, coords, out);
}

// Round 10
// 37.441 us; speedup vs baseline: 2.0350x; 1.3169x over previous
//
#include <hip/hip_runtime.h>

// s[n,k] = x[n]·coords[k] + ||coords[k]||^2 ; out[n,k] = (second_min_j s[n,j]) > s[n,k]
// 512 blocks x 512 threads. Block: 32 rows x 128 cols. wave = K-split g (8 x 32 dims).
// Thread: 8x8 tile. 4 chunks x 8 dims/split. xs slot-XOR swizzle; cs col fold-swizzle.
// __launch_bounds__(512, 2): empirically arg2 = min BLOCKS/CU (R7/R8/R9 triangulation)
// -> 2 blocks/CU, VGPR cap 128 (~115 needed, no spill), 16 waves/CU.

__global__ __launch_bounds__(512, 2)
void kmad_main(const float* __restrict__ x, const float* __restrict__ coords,
               int* __restrict__ out) {
    __shared__ float lds[17024];         // 66.5 KB
    float* const cs    = lds;            // [64][128], col f4-slot S stored at S^(S>>3)
    float* const xs    = lds + 8192;     // [32][64], f4-slot sk stored at sk^(row>>3)
    float* const norms = lds + 16896;    // [128]
    float* const part  = lds;            // epilogue alias [4][32][132] = 16896 floats

    const int t  = threadIdx.x;
    const int g  = t >> 6;               // wave = K-split 0..7 (owns dims g*32..+32)
    const int l  = t & 63;
    const int rg = l >> 4;               // 0..3 -> rows rg*8..+8
    const int cg = l & 15;               // 0..15 -> cols cg*8..+8
    const int r0 = rg * 8;
    const int row0 = blockIdx.x * 32;

    const int S0  = cg * 2, S1 = S0 + 1;
    const int pc0 = (S0 ^ (S0 >> 3)) * 4;
    const int pc1 = (S1 ^ (S1 >> 3)) * 4;

    // ---- norms[c] = ||coords[c]||^2 ----
    {
        const int c = t >> 2, h = t & 3;
        const float4* cp = (const float4*)(coords + (size_t)c * 256 + h * 64);
        float na = 0.f;
        #pragma unroll
        for (int k = 0; k < 16; ++k) {
            const float4 v = cp[k];
            na = fmaf(v.x, v.x, na); na = fmaf(v.y, v.y, na);
            na = fmaf(v.z, v.z, na); na = fmaf(v.w, v.w, na);
        }
        na += __shfl_xor(na, 1); na += __shfl_xor(na, 2);
        if (h == 0) norms[c] = na;
    }

    // ---- staging roles ----
    const int srow = t >> 4, sk = t & 15;
    const int xso  = srow * 64 + ((sk ^ (srow >> 3)) * 4);
    const float* xr = x + (size_t)(row0 + srow) * 256 + ((sk >> 1) * 32 + (sk & 1) * 4);
    const int cq = t & 31, dsel = t >> 5;     // dsel 0..15
    const int Pq = (cq ^ (cq >> 3)) * 4;
    const float* crd = coords + (size_t)(cq * 4) * 256
                     + ((dsel >> 1) * 32 + (dsel & 1) * 4);    // + ch*8 at use
    float* const csw = cs + (size_t)(dsel * 4) * 128 + Pq;

#define STAGE(CH) { \
        *(float4*)(xs + xso) = *(const float4*)(xr + (CH) * 8); \
        const float4 u0 = *(const float4*)(crd + (CH) * 8); \
        const float4 u1 = *(const float4*)(crd + (CH) * 8 + 256); \
        const float4 u2 = *(const float4*)(crd + (CH) * 8 + 512); \
        const float4 u3 = *(const float4*)(crd + (CH) * 8 + 768); \
        *(float4*)(csw)       = make_float4(u0.x, u1.x, u2.x, u3.x); \
        *(float4*)(csw + 128) = make_float4(u0.y, u1.y, u2.y, u3.y); \
        *(float4*)(csw + 256) = make_float4(u0.z, u1.z, u2.z, u3.z); \
        *(float4*)(csw + 384) = make_float4(u0.w, u1.w, u2.w, u3.w); \
    }

    STAGE(0)
    __syncthreads();

    float acc[8][8] = {};

    #pragma unroll
    for (int ch = 0; ch < 4; ++ch) {
        #pragma unroll
        for (int dd = 0; dd < 2; ++dd) {
            const int sl = g * 2 + dd;
            const float* br = cs + (size_t)(g * 8 + dd * 4) * 128;
            float4 b0[4], b1[4];
            #pragma unroll
            for (int j = 0; j < 4; ++j) {
                b0[j] = *(const float4*)(br + j * 128 + pc0);
                b1[j] = *(const float4*)(br + j * 128 + pc1);
            }
            #pragma unroll
            for (int i = 0; i < 8; ++i) {
                const float4 a = *(const float4*)(xs + (r0 + i) * 64 + ((sl ^ rg) * 4));
#define STEP(j, av) \
                acc[i][0] = fmaf(av, b0[j].x, acc[i][0]); \
                acc[i][1] = fmaf(av, b0[j].y, acc[i][1]); \
                acc[i][2] = fmaf(av, b0[j].z, acc[i][2]); \
                acc[i][3] = fmaf(av, b0[j].w, acc[i][3]); \
                acc[i][4] = fmaf(av, b1[j].x, acc[i][4]); \
                acc[i][5] = fmaf(av, b1[j].y, acc[i][5]); \
                acc[i][6] = fmaf(av, b1[j].z, acc[i][6]); \
                acc[i][7] = fmaf(av, b1[j].w, acc[i][7]);
                STEP(0, a.x) STEP(1, a.y) STEP(2, a.z) STEP(3, a.w)
#undef STEP
            }
        }
        __syncthreads();
        if (ch < 3) STAGE(ch + 1)
        __syncthreads();
    }
#undef STAGE

    // ---- reduce 8 split-partials via 4 planes, 2 rounds ----
    if (g < 4) {
        float* pl = part + g * 4224 + (size_t)r0 * 132 + cg * 8;
        #pragma unroll
        for (int i = 0; i < 8; ++i) {
            *(float4*)(pl + i * 132)     = make_float4(acc[i][0], acc[i][1], acc[i][2], acc[i][3]);
            *(float4*)(pl + i * 132 + 4) = make_float4(acc[i][4], acc[i][5], acc[i][6], acc[i][7]);
        }
    }
    __syncthreads();
    if (g >= 4) {
        float* pl = part + (g - 4) * 4224 + (size_t)r0 * 132 + cg * 8;
        #pragma unroll
        for (int i = 0; i < 8; ++i) {
            float4 v0 = *(const float4*)(pl + i * 132);
            float4 v1 = *(const float4*)(pl + i * 132 + 4);
            v0.x += acc[i][0]; v0.y += acc[i][1]; v0.z += acc[i][2]; v0.w += acc[i][3];
            v1.x += acc[i][4]; v1.y += acc[i][5]; v1.z += acc[i][6]; v1.w += acc[i][7];
            *(float4*)(pl + i * 132)     = v0;
            *(float4*)(pl + i * 132 + 4) = v1;
        }
    }
    __syncthreads();

    // ---- final: sum 4 planes, +norms, second-min over 128, compare, store ----
    {
        const int frow = t >> 4, seg = t & 15;       // 32 rows x 16 col-segments of 8
        const float* pr = part + (size_t)frow * 132 + seg * 8;
        float s[8];
        #pragma unroll
        for (int u = 0; u < 2; ++u) {
            const float4 a = *(const float4*)(pr + u * 4);
            const float4 b = *(const float4*)(pr + 4224  + u * 4);
            const float4 c = *(const float4*)(pr + 8448  + u * 4);
            const float4 d = *(const float4*)(pr + 12672 + u * 4);
            const float4 n = *(const float4*)(norms + seg * 8 + u * 4);
            s[u * 4 + 0] = (a.x + b.x) + (c.x + d.x) + n.x;
            s[u * 4 + 1] = (a.y + b.y) + (c.y + d.y) + n.y;
            s[u * 4 + 2] = (a.z + b.z) + (c.z + d.z) + n.z;
            s[u * 4 + 3] = (a.w + b.w) + (c.w + d.w) + n.w;
        }
        float m1 = fminf(s[0], s[1]);
        float m2 = fmaxf(s[0], s[1]);
#define UPD(v) { const float hi = fmaxf(m1, (v)); m1 = fminf(m1, (v)); m2 = fminf(m2, hi); }
        UPD(s[2]) UPD(s[3]) UPD(s[4]) UPD(s[5]) UPD(s[6]) UPD(s[7])
#undef UPD
        #pragma unroll
        for (int m = 1; m <= 8; m <<= 1) {   // merge across the 16 seg lanes
            const float o1 = __shfl_xor(m1, m);
            const float o2 = __shfl_xor(m2, m);
            m2 = fminf(fmaxf(m1, o1), fminf(m2, o2));
            m1 = fminf(m1, o1);
        }
        int* op = out + (size_t)(row0 + frow) * 128 + seg * 8;
        int4 o0, o1v;
        o0.x  = m2 > s[0]; o0.y  = m2 > s[1]; o0.z  = m2 > s[2]; o0.w  = m2 > s[3];
        o1v.x = m2 > s[4]; o1v.y = m2 > s[5]; o1v.z = m2 > s[6]; o1v.w = m2 > s[7];
        *(int4*)op       = o0;
        *(int4*)(op + 4) = o1v;
    }
}

extern "C" void kernel_launch(void* const* d_in, const int* in_sizes, int n_in,
                              void* d_out, int out_size, void* d_ws, size_t ws_size,
                              hipStream_t stream) {
    const float* x      = (const float*)d_in[0];   // (16384, 256) fp32
    const float* coords = (const float*)d_in[1];   // (128, 256)   fp32
    int* out = (int*)d_out;                        // (16384, 128) bool -> int32 0/1
    kmad_main<<<512, 512, 0, stream>>>(x, coords, out);
}